// Round 1
// 571.519 us; speedup vs baseline: 1.0400x; 1.0400x over previous
//
#include <hip/hip_runtime.h>

// Problem constants (from reference)
#define B_      4
#define N_      200000
#define C_      96
#define S_      32
#define EPS_    1e-5f

#define C4      (C_ / 4)          // 24 float4 per point
#define NC4     (N_ * C4)         // 4,800,000 float4 per batch
#define THREADS 256
#define ITER    30                // 30*256 = 7680 divides 4,800,000 exactly -> NO tail, NO break
#define CHUNK   (THREADS * ITER)  // 7680 float4 per block
#define GRIDX   (NC4 / CHUNK)     // 625 (exact)
#define GROUPS  (ITER / 3)        // 10 (period-3 channel phase)

typedef float f32x4 __attribute__((ext_vector_type(4)));

__device__ __forceinline__ float4 scale4(const float4 a, const float s) {
    return make_float4(a.x * s, a.y * s, a.z * s, a.w * s);
}
// bb - m*fw (component-wise)
__device__ __forceinline__ float4 nms4(const float4 bb, const float m, const float4 fw) {
    return make_float4(bb.x - m * fw.x, bb.y - m * fw.y, bb.z - m * fw.z, bb.w - m * fw.w);
}

// ---------------------------------------------------------------------------
// Pass 1: per-(b,s) sum / sum-of-squares.
// Segments are contiguous point ranges -> derive segment id from the 33-entry
// offsets table (LDS) + incremental (n,c) tracking. No per-element gather of
// batch_indices, no per-element integer division, no tail branch.
// Per-iteration: 1 coalesced 16B load + ~13 VALU.
// ---------------------------------------------------------------------------
__global__ __launch_bounds__(THREADS) void stats_kernel(
    const float4* __restrict__ x,
    const int*    __restrict__ offsets,    // batch_offsets [S+1] (int32)
    float*        __restrict__ gsum,       // [B*S]
    float*        __restrict__ gsq)        // [B*S]
{
    __shared__ int   soff[S_ + 1];
    __shared__ float lsum[S_];
    __shared__ float lsq [S_];
    const int t = threadIdx.x;
    if (t <= S_) soff[t] = offsets[t];
    if (t <  S_) { lsum[t] = 0.f; lsq[t] = 0.f; }
    __syncthreads();

    const int b = blockIdx.y;
    const float4* xb = x + (size_t)b * NC4;
    const int f0 = blockIdx.x * CHUNK + t;

    // initial point index / channel-quad phase
    int n = f0 / 24;            // one division per thread, not per element
    int c = f0 - n * 24;
    // binary search: largest sg with soff[sg] <= n  (soff[0]=0, soff[32]=N)
    int sg = 0;
    #pragma unroll
    for (int st = 16; st; st >>= 1) {
        const int cand = sg + st;           // cand <= 31 always
        if (soff[cand] <= n) sg = cand;
    }
    int nxt = soff[sg + 1];

    float s1 = 0.f, s2 = 0.f;
    for (int k = 0; k < ITER; ++k) {
        if (n >= nxt) {                      // rare: crossed a segment boundary
            atomicAdd(&lsum[sg], s1);
            atomicAdd(&lsq [sg], s2);
            s1 = 0.f; s2 = 0.f;
            do { ++sg; } while (soff[sg + 1] <= n);   // soff[32]=N stops walk
            nxt = soff[sg + 1];
        }
        const float4 v = xb[f0 + k * THREADS];
        s1 += (v.x + v.y) + (v.z + v.w);
        s2 += v.x * v.x + v.y * v.y + v.z * v.z + v.w * v.w;
        // advance one stride of 256 float4 = 10 points + 16 channel-quads
        c += 16; if (c >= 24) { c -= 24; ++n; }
        n += 10;
    }
    atomicAdd(&lsum[sg], s1);
    atomicAdd(&lsq [sg], s2);
    __syncthreads();

    if (t < S_) {
        const float a = lsum[t];
        const float q = lsq[t];
        if (a != 0.f || q != 0.f) {
            atomicAdd(&gsum[b * S_ + t], a);
            atomicAdd(&gsq [b * S_ + t], q);
        }
    }
}

// ---------------------------------------------------------------------------
// Pass 2 (tiny): mean / rstd per (b,s)
// ---------------------------------------------------------------------------
__global__ void finalize_kernel(
    const float* __restrict__ gsum,
    const float* __restrict__ gsq,
    const int*   __restrict__ offsets,
    float*       __restrict__ mean,        // [B*S]
    float*       __restrict__ rstd)        // [B*S]
{
    const int i = threadIdx.x;
    if (i < B_ * S_) {
        const int s = i % S_;
        const float cnt = (float)(offsets[s + 1] - offsets[s]) * (float)C_;
        const float m = gsum[i] / cnt;
        const float v = gsq[i] / cnt - m * m;
        mean[i] = m;
        rstd[i] = rsqrtf(fmaxf(v, 0.f) + EPS_);
    }
}

// ---------------------------------------------------------------------------
// Pass 3: out = x*fw + fb, with fw = rstd*w[c], fb = bias[c] - mean*fw,
// recomputed only on segment change. Each thread's channel-quad index cycles
// with period 3 -> 3 register-cached (fw,fb) pairs, statically indexed via a
// manually 3-unrolled loop (rule: no runtime register indexing).
// Chunk traversed DESCENDING: after the forward stats pass the most recently
// read ~83% of x (307MB vs 256MB L3) is still L3-resident; newest-first reads
// hit instead of LRU-thrashing. out is written with nontemporal stores so the
// write stream does not evict x from L2/L3.
// ---------------------------------------------------------------------------
__global__ __launch_bounds__(THREADS) void norm_kernel(
    const float4* __restrict__ x,
    const int*    __restrict__ offsets,
    const float4* __restrict__ wgt,        // [24] float4
    const float4* __restrict__ bia,        // [24] float4
    const float*  __restrict__ mean,
    const float*  __restrict__ rstd,
    float4*       __restrict__ out)
{
    __shared__ int    soff[S_ + 1];
    __shared__ float4 lw[C4];
    __shared__ float4 lb[C4];
    __shared__ float  lm[S_];
    __shared__ float  lr[S_];
    const int t = threadIdx.x;
    const int b = blockIdx.y;
    if (t <= S_) soff[t] = offsets[t];
    if (t <  C4) { lw[t] = wgt[t]; lb[t] = bia[t]; }
    if (t <  S_) { lm[t] = mean[b * S_ + t]; lr[t] = rstd[b * S_ + t]; }
    __syncthreads();

    const float4* xb = x   + (size_t)b * NC4;
    float4*       ob = out + (size_t)b * NC4;
    const int f0 = blockIdx.x * CHUNK + t;

    // channel-quad phase classes: k%3==0 -> c0, ==1 -> c1, ==2 -> c2
    const int c0 = f0 - (f0 / 24) * 24;
    int c1 = c0 + 16; if (c1 >= 24) c1 -= 24;
    int c2 = c0 + 8;  if (c2 >= 24) c2 -= 24;

    // start at the END of the chunk (k = ITER-1), walk down
    const int fhi = f0 + (ITER - 1) * THREADS;
    int n = fhi / 24;
    int c = fhi - n * 24;

    int sg = 0;
    #pragma unroll
    for (int st = 16; st; st >>= 1) {
        const int cand = sg + st;
        if (soff[cand] <= n) sg = cand;
    }
    int lo = soff[sg];

    float4 fw0, fb0, fw1, fb1, fw2, fb2;
#define RECOMP() { \
        const float m_ = lm[sg], r_ = lr[sg]; \
        fw0 = scale4(lw[c0], r_); fb0 = nms4(lb[c0], m_, fw0); \
        fw1 = scale4(lw[c1], r_); fb1 = nms4(lb[c1], m_, fw1); \
        fw2 = scale4(lw[c2], r_); fb2 = nms4(lb[c2], m_, fw2); \
    }
    RECOMP();

#define NBODY(K, J) { \
        if (n < lo) {                                   /* rare */ \
            do { --sg; } while (n < soff[sg]);          /* soff[0]=0 stops */ \
            lo = soff[sg]; \
            RECOMP(); \
        } \
        const int fi = f0 + (K) * THREADS; \
        const float4 v = xb[fi]; \
        float4 o; \
        o.x = v.x * fw##J.x + fb##J.x; \
        o.y = v.y * fw##J.y + fb##J.y; \
        o.z = v.z * fw##J.z + fb##J.z; \
        o.w = v.w * fw##J.w + fb##J.w; \
        __builtin_nontemporal_store(*(const f32x4*)&o, (f32x4*)(ob + fi)); \
        c -= 16; if (c < 0) { c += 24; --n; } \
        n -= 10; \
    }

    for (int g = GROUPS - 1; g >= 0; --g) {
        NBODY(3 * g + 2, 2)
        NBODY(3 * g + 1, 1)
        NBODY(3 * g + 0, 0)
    }
#undef NBODY
#undef RECOMP
}

// ---------------------------------------------------------------------------
extern "C" void kernel_launch(void* const* d_in, const int* in_sizes, int n_in,
                              void* d_out, int out_size, void* d_ws, size_t ws_size,
                              hipStream_t stream)
{
    const float* x       = (const float*)d_in[0];
    const int*   offsets = (const int*)  d_in[1];
    const int*   indices = (const int*)  d_in[2];   // unused now (offsets suffice)
    const float* weight  = (const float*)d_in[3];
    const float* bias    = (const float*)d_in[4];
    float*       out     = (float*)d_out;
    (void)indices; (void)in_sizes; (void)n_in; (void)out_size; (void)ws_size;

    float* gsum = (float*)d_ws;          // [B*S]
    float* gsq  = gsum + B_ * S_;        // [B*S]
    float* mean = gsq  + B_ * S_;        // [B*S]
    float* rstd = mean + B_ * S_;        // [B*S]

    // ws is poisoned to 0xAA before every timed call — zero the accumulators.
    hipMemsetAsync(d_ws, 0, 2 * B_ * S_ * sizeof(float), stream);

    dim3 grid(GRIDX, B_);
    stats_kernel<<<grid, THREADS, 0, stream>>>(
        (const float4*)x, offsets, gsum, gsq);

    finalize_kernel<<<1, 128, 0, stream>>>(gsum, gsq, offsets, mean, rstd);

    norm_kernel<<<grid, THREADS, 0, stream>>>(
        (const float4*)x, offsets, (const float4*)weight, (const float4*)bias,
        mean, rstd, (float4*)out);
}